// Round 8
// baseline (131.214 us; speedup 1.0000x reference)
//
#include <hip/hip_runtime.h>
#include <hip/hip_bf16.h>

typedef unsigned short u16;
typedef u16 u16x4 __attribute__((ext_vector_type(4)));
typedef u16 u16x8 __attribute__((ext_vector_type(8)));
typedef __bf16 bf16x8 __attribute__((ext_vector_type(8)));
typedef float f32x4 __attribute__((ext_vector_type(4)));

static __device__ __forceinline__ u16 f2bf(float f) {
  return __builtin_bit_cast(u16, __float2bfloat16(f));   // RTNE
}

// async global->LDS, 16B per lane. LDS dest = wave-uniform base + lane*16.
static __device__ __forceinline__ void gload16(const u16* g, u16* l) {
  __builtin_amdgcn_global_load_lds(
      (const __attribute__((address_space(1))) unsigned*)g,
      (__attribute__((address_space(3))) unsigned*)l, 16, 0, 0);
}

#define WAIT8_BAR() asm volatile("s_waitcnt vmcnt(8)\ns_barrier" ::: "memory")
#define WAIT0_BAR() asm volatile("s_waitcnt vmcnt(0)\ns_barrier" ::: "memory")
#define BAR()       asm volatile("s_barrier" ::: "memory")

// ---------------- x f32 -> bf16 ----------------
__global__ __launch_bounds__(256) void cvt_x_kernel(const float* __restrict__ in,
                                                    u16* __restrict__ out) {
  int i = blockIdx.x * 256 + threadIdx.x;          // 8 elems per thread
  const float4* p = reinterpret_cast<const float4*>(in) + (size_t)i * 2;
  float4 a = p[0], b = p[1];
  u16x8 o;
  o[0] = f2bf(a.x); o[1] = f2bf(a.y); o[2] = f2bf(a.z); o[3] = f2bf(a.w);
  o[4] = f2bf(b.x); o[5] = f2bf(b.y); o[6] = f2bf(b.z); o[7] = f2bf(b.w);
  reinterpret_cast<u16x8*>(out)[i] = o;
}

// ---------------- W [768][2304] f32 -> WbT [2304][768] bf16 ----------------
__global__ __launch_bounds__(256) void cvt_wT_kernel(const float* __restrict__ W,
                                                     u16* __restrict__ WT) {
  int n  = blockIdx.x * 256 + threadIdx.x;   // 0..2303 (gridDim.x = 9)
  int k0 = blockIdx.y * 4;                   // gridDim.y = 192
  u16x4 o;
#pragma unroll
  for (int j = 0; j < 4; ++j) o[j] = f2bf(W[(size_t)(k0 + j) * 2304 + n]);
  *reinterpret_cast<u16x4*>(WT + (size_t)n * 768 + k0) = o;
}

// ---------------- QKV GEMM: [8192x768] @ [768x2304] + bias ----------------
// BK=64, both-sides XOR swizzle (chunk c stored at c^(row&7); pre-swizzled
// global source keeps global_load_lds dest linear). 2-deep counted vmcnt(8).
// LDS rows 128B: swizzled read verified 2-way bank alias (free).
// writes q[bh][t][d], k[bh][t][d], vT[bh][d][t]  (all bf16)

static __device__ __forceinline__ void gemm_compute64(
    const u16* __restrict__ as, const u16* __restrict__ bs,
    int wm, int wn, int l16, int g, f32x4 (&acc)[4][4]) {
  bf16x8 af[4][2], bfr[4][2];
#pragma unroll
  for (int mi = 0; mi < 4; ++mi)
#pragma unroll
    for (int ks = 0; ks < 2; ++ks)
      af[mi][ks] = __builtin_bit_cast(bf16x8,
          *reinterpret_cast<const u16x8*>(
              as + (wm + mi * 16 + l16) * 64 + (((ks * 4 + g) ^ (l16 & 7)) * 8)));
#pragma unroll
  for (int ni = 0; ni < 4; ++ni)
#pragma unroll
    for (int ks = 0; ks < 2; ++ks)
      bfr[ni][ks] = __builtin_bit_cast(bf16x8,
          *reinterpret_cast<const u16x8*>(
              bs + (wn + ni * 16 + l16) * 64 + (((ks * 4 + g) ^ (l16 & 7)) * 8)));
#pragma unroll
  for (int ks = 0; ks < 2; ++ks)
#pragma unroll
    for (int mi = 0; mi < 4; ++mi)
#pragma unroll
      for (int ni = 0; ni < 4; ++ni)
        acc[mi][ni] = __builtin_amdgcn_mfma_f32_16x16x32_bf16(
            af[mi][ks], bfr[ni][ks], acc[mi][ni], 0, 0, 0);
}

__global__ __launch_bounds__(256, 2) void gemm_qkv_kernel(
    const u16* __restrict__ A, const u16* __restrict__ Bt,
    const float* __restrict__ bias,
    u16* __restrict__ qb, u16* __restrict__ kb, u16* __restrict__ vTb) {
  __shared__ __align__(16) u16 as0[128 * 64], as1[128 * 64];
  __shared__ __align__(16) u16 bs0[128 * 64], bs1[128 * 64];
  const int K = 768;
  int tid = threadIdx.x;
  int lane = tid & 63;
  int wave = tid >> 6;

  int m0 = blockIdx.x * 128;       // gridDim.x = 64 (m%8==XCD -> per-XCD L2-fit)
  int n0 = blockIdx.y * 128;       // gridDim.y = 18

  int wm = (wave >> 1) * 64;
  int wn = (wave & 1) * 64;
  int l16 = lane & 15, g = lane >> 4;

  // staging: wave w owns rows [w*32, w*32+32). Each instr covers 8 rows
  // (8 lanes/row x 16B). Lane reads global chunk (l&7)^((l>>3)&7) so the
  // linear LDS dest receives the swizzled layout (rule #21).
  int r8 = lane >> 3;
  int cs = (lane & 7) ^ (r8 & 7);
  const u16* gA = A  + (size_t)(m0 + wave * 32 + r8) * K + cs * 8;
  const u16* gB = Bt + (size_t)(n0 + wave * 32 + r8) * K + cs * 8;
  int lofs = wave * 2048;   // elems (32 rows x 64); +512/instr (8 rows)

  f32x4 acc[4][4];
#pragma unroll
  for (int mi = 0; mi < 4; ++mi)
#pragma unroll
    for (int ni = 0; ni < 4; ++ni) acc[mi][ni] = (f32x4){0.f, 0.f, 0.f, 0.f};

#define STAGE(Abuf, Bbuf, kk)                              \
  do {                                                     \
    gload16(gA + (kk),           Abuf + lofs);             \
    gload16(gA + (kk) +  8 * K,  Abuf + lofs + 512);       \
    gload16(gA + (kk) + 16 * K,  Abuf + lofs + 1024);      \
    gload16(gA + (kk) + 24 * K,  Abuf + lofs + 1536);      \
    gload16(gB + (kk),           Bbuf + lofs);             \
    gload16(gB + (kk) +  8 * K,  Bbuf + lofs + 512);       \
    gload16(gB + (kk) + 16 * K,  Bbuf + lofs + 1024);      \
    gload16(gB + (kk) + 24 * K,  Bbuf + lofs + 1536);      \
  } while (0)

  // prologue: chunks 0,1 in flight (16 loads)
  STAGE(as0, bs0, 0);
  STAGE(as1, bs1, 64);
  for (int j = 0; j < 5; ++j) {
    int k0 = j * 128;
    WAIT8_BAR();                        // chunk 2j landed; newest 8 in flight
    gemm_compute64(as0, bs0, wm, wn, l16, g, acc);
    BAR();
    STAGE(as0, bs0, k0 + 128);
    WAIT8_BAR();                        // chunk 2j+1 landed
    gemm_compute64(as1, bs1, wm, wn, l16, g, acc);
    BAR();
    STAGE(as1, bs1, k0 + 192);
  }
  // peel: chunks k=640 (as0), k=704 (as1)
  WAIT8_BAR();
  gemm_compute64(as0, bs0, wm, wn, l16, g, acc);
  WAIT0_BAR();
  gemm_compute64(as1, bs1, wm, wn, l16, g, acc);
#undef STAGE

  // epilogue: bias + scatter to q/k/vT (bf16)
  int tbase = m0 & 1023;
  int b = m0 >> 10;
  int g4 = g * 4;
#pragma unroll
  for (int ni = 0; ni < 4; ++ni) {
    int n = n0 + wn + ni * 16 + l16;
    float bv = bias[n];
    int region = n / 768;
    int c = n - region * 768;
    int h = c >> 6, d = c & 63;
    int bh = b * 12 + h;
#pragma unroll
    for (int mi = 0; mi < 4; ++mi) {
      int t0 = tbase + wm + mi * 16 + g4;
      if (region == 2) {
        u16x4 pv;
#pragma unroll
        for (int r = 0; r < 4; ++r) pv[r] = f2bf(acc[mi][ni][r] + bv);
        *reinterpret_cast<u16x4*>(vTb + ((size_t)bh * 64 + d) * 1024 + t0) = pv;
      } else {
        u16* dst = (region == 0) ? qb : kb;
#pragma unroll
        for (int r = 0; r < 4; ++r)
          dst[((size_t)bh * 1024 + t0 + r) * 64 + d] = f2bf(acc[mi][ni][r] + bv);
      }
    }
  }
}

// ---------------- causal relu attention ----------------
// y[b,h,q,:] = sum_{k<=q} relu(scale * q.k) * v[k]
// Wave-uniform pairing: wave t handles q-groups q0a=16t and q0b=1008-16t
// (16 rows each) -> every wave runs exactly 17 key-tiles (KVBLK=64), shared
// K/V loads over the common prefix. K double-buffered: QK^T(t+1) consumes
// K loaded one full iteration earlier.
__global__ __launch_bounds__(256) void attn_kernel(
    const u16* __restrict__ qb, const u16* __restrict__ kb,
    const u16* __restrict__ vTb, float* __restrict__ out) {
  __shared__ __align__(16) u16 plds[4][2 * 16 * 72];
  int lane = threadIdx.x & 63;
  int wave = threadIdx.x >> 6;
  int bh = blockIdx.x;                           // 0..95
  int t = blockIdx.y * 4 + wave;                 // 0..31
  int q0a = t * 16;
  int q0b = 1008 - t * 16;
  int ntA = (q0a >> 6) + 1;
  int ntB = (q0b >> 6) + 1;                      // ntA + ntB == 17
  int qoffA = q0a & 63, qoffB = q0b & 63;
  int b = bh / 12, h = bh - b * 12;
  const u16* Q  = qb  + (size_t)bh * 65536;
  const u16* Kp = kb  + (size_t)bh * 65536;
  const u16* Vt = vTb + (size_t)bh * 65536;
  int l16 = lane & 15, g = lane >> 4;
  u16* pwA = &plds[wave][0];
  u16* pwB = pwA + 16 * 72;

  bf16x8 qfA[2], qfB[2];
#pragma unroll
  for (int ks = 0; ks < 2; ++ks) {
    qfA[ks] = __builtin_bit_cast(bf16x8,
        *reinterpret_cast<const u16x8*>(Q + (q0a + l16) * 64 + ks * 32 + g * 8));
    qfB[ks] = __builtin_bit_cast(bf16x8,
        *reinterpret_cast<const u16x8*>(Q + (q0b + l16) * 64 + ks * 32 + g * 8));
  }

  f32x4 yA[4], yB[4];
#pragma unroll
  for (int ni = 0; ni < 4; ++ni) {
    yA[ni] = (f32x4){0.f, 0.f, 0.f, 0.f};
    yB[ni] = (f32x4){0.f, 0.f, 0.f, 0.f};
  }

  // S^T lane layout (16-row group): q col = l16, key row = kj*16 + g*4 + r
  f32x4 sA[4], sB[4];
  u16x8 knA[4][2], knB[4][2];

  // prologue: K(0) -> scratch knB, compute S(0); then knA = K(1)
#pragma unroll
  for (int kj = 0; kj < 4; ++kj)
#pragma unroll
    for (int ks = 0; ks < 2; ++ks)
      knB[kj][ks] = *reinterpret_cast<const u16x8*>(
          Kp + (kj * 16 + l16) * 64 + ks * 32 + g * 8);
#pragma unroll
  for (int kj = 0; kj < 4; ++kj) {
    sA[kj] = (f32x4){0.f, 0.f, 0.f, 0.f};
    sB[kj] = (f32x4){0.f, 0.f, 0.f, 0.f};
  }
#pragma unroll
  for (int ks = 0; ks < 2; ++ks)
#pragma unroll
    for (int kj = 0; kj < 4; ++kj) {
      bf16x8 kf = __builtin_bit_cast(bf16x8, knB[kj][ks]);
      if (ntA > 0)   // always true; keeps symmetry
        sA[kj] = __builtin_amdgcn_mfma_f32_16x16x32_bf16(kf, qfA[ks], sA[kj], 0, 0, 0);
      sB[kj] = __builtin_amdgcn_mfma_f32_16x16x32_bf16(kf, qfB[ks], sB[kj], 0, 0, 0);
    }
#pragma unroll
  for (int kj = 0; kj < 4; ++kj)
#pragma unroll
    for (int ks = 0; ks < 2; ++ks)
      knA[kj][ks] = *reinterpret_cast<const u16x8*>(
          Kp + (64 + kj * 16 + l16) * 64 + ks * 32 + g * 8);

  auto body = [&](u16x8 (&kcur)[4][2], u16x8 (&knext)[4][2], int kt) {
    int kb0 = kt << 6;
    bool actA = kt < ntA;
    bool nxtA = kt + 1 < ntA;
    bool nxtB = kt + 1 < ntB;

    // 1) V(kt) loads (used step 4) + K(kt+2) loads (used NEXT iter step 3)
    u16x8 vf[4][2];
#pragma unroll
    for (int ni = 0; ni < 4; ++ni)
#pragma unroll
      for (int kc = 0; kc < 2; ++kc)
        vf[ni][kc] = *reinterpret_cast<const u16x8*>(
            Vt + (ni * 16 + l16) * 1024 + kb0 + kc * 32 + g * 8);
    if (kt + 2 < ntB) {
#pragma unroll
      for (int kj = 0; kj < 4; ++kj)
#pragma unroll
        for (int ks = 0; ks < 2; ++ks)
          knext[kj][ks] = *reinterpret_cast<const u16x8*>(
              Kp + (kb0 + 128 + kj * 16 + l16) * 64 + ks * 32 + g * 8);
    }

    // 2) pack P(kt): scale, relu, diag mask; LDS write (b64 per kj)
    if (actA) {
      bool dA = (kt == ntA - 1);
#pragma unroll
      for (int kj = 0; kj < 4; ++kj) {
        u16x4 pv;
#pragma unroll
        for (int r = 0; r < 4; ++r) {
          float v = fmaxf(sA[kj][r] * 0.125f, 0.f);
          if (dA && (kj * 16 + g * 4 + r > qoffA + l16)) v = 0.f;
          pv[r] = f2bf(v);
        }
        *reinterpret_cast<u16x4*>(pwA + l16 * 72 + kj * 16 + g * 4) = pv;
      }
    }
    {
      bool dB = (kt == ntB - 1);
#pragma unroll
      for (int kj = 0; kj < 4; ++kj) {
        u16x4 pv;
#pragma unroll
        for (int r = 0; r < 4; ++r) {
          float v = fmaxf(sB[kj][r] * 0.125f, 0.f);
          if (dB && (kj * 16 + g * 4 + r > qoffB + l16)) v = 0.f;
          pv[r] = f2bf(v);
        }
        *reinterpret_cast<u16x4*>(pwB + l16 * 72 + kj * 16 + g * 4) = pv;
      }
    }

    __builtin_amdgcn_s_setprio(1);
    // 3) QK^T(kt+1) from kcur (loaded a full iteration ago)
    if (nxtA) {
#pragma unroll
      for (int kj = 0; kj < 4; ++kj) sA[kj] = (f32x4){0.f, 0.f, 0.f, 0.f};
#pragma unroll
      for (int ks = 0; ks < 2; ++ks)
#pragma unroll
        for (int kj = 0; kj < 4; ++kj)
          sA[kj] = __builtin_amdgcn_mfma_f32_16x16x32_bf16(
              __builtin_bit_cast(bf16x8, kcur[kj][ks]), qfA[ks], sA[kj], 0, 0, 0);
    }
    if (nxtB) {
#pragma unroll
      for (int kj = 0; kj < 4; ++kj) sB[kj] = (f32x4){0.f, 0.f, 0.f, 0.f};
#pragma unroll
      for (int ks = 0; ks < 2; ++ks)
#pragma unroll
        for (int kj = 0; kj < 4; ++kj)
          sB[kj] = __builtin_amdgcn_mfma_f32_16x16x32_bf16(
              __builtin_bit_cast(bf16x8, kcur[kj][ks]), qfB[ks], sB[kj], 0, 0, 0);
    }

    // 4) read P(kt), PV(kt)
    if (actA) {
      bf16x8 pa[2];
#pragma unroll
      for (int kc = 0; kc < 2; ++kc)
        pa[kc] = __builtin_bit_cast(bf16x8,
            *reinterpret_cast<const u16x8*>(pwA + l16 * 72 + kc * 32 + g * 8));
#pragma unroll
      for (int kc = 0; kc < 2; ++kc)
#pragma unroll
        for (int ni = 0; ni < 4; ++ni)
          yA[ni] = __builtin_amdgcn_mfma_f32_16x16x32_bf16(
              pa[kc], __builtin_bit_cast(bf16x8, vf[ni][kc]), yA[ni], 0, 0, 0);
    }
    {
      bf16x8 pa[2];
#pragma unroll
      for (int kc = 0; kc < 2; ++kc)
        pa[kc] = __builtin_bit_cast(bf16x8,
            *reinterpret_cast<const u16x8*>(pwB + l16 * 72 + kc * 32 + g * 8));
#pragma unroll
      for (int kc = 0; kc < 2; ++kc)
#pragma unroll
        for (int ni = 0; ni < 4; ++ni)
          yB[ni] = __builtin_amdgcn_mfma_f32_16x16x32_bf16(
              pa[kc], __builtin_bit_cast(bf16x8, vf[ni][kc]), yB[ni], 0, 0, 0);
    }
    __builtin_amdgcn_s_setprio(0);
  };

  for (int kt = 0; kt < ntB; ++kt) {
    if (kt & 1) body(knB, knA, kt);
    else        body(knA, knB, kt);
  }

  // out[b, t, h*64+d] f32; q row = g*4 + r
  float* outp = out + (size_t)b * 1024 * 768 + (size_t)h * 64;
#pragma unroll
  for (int r = 0; r < 4; ++r) {
    int ta = q0a + g * 4 + r, tb = q0b + g * 4 + r;
#pragma unroll
    for (int ni = 0; ni < 4; ++ni) {
      outp[(size_t)ta * 768 + ni * 16 + l16] = yA[ni][r];
      outp[(size_t)tb * 768 + ni * 16 + l16] = yB[ni][r];
    }
  }
}

extern "C" void kernel_launch(void* const* d_in, const int* in_sizes, int n_in,
                              void* d_out, int out_size, void* d_ws, size_t ws_size,
                              hipStream_t stream) {
  const float* x    = (const float*)d_in[0];
  const float* W    = (const float*)d_in[1];
  const float* bias = (const float*)d_in[2];
  float* out = (float*)d_out;
  char* ws = (char*)d_ws;

  // ws layout (bytes): xb 12.58MB | WbT 3.54MB | qb 12.58MB | kb 12.58MB | vTb 12.58MB
  u16* xb  = (u16*)(ws);
  u16* WbT = (u16*)(ws + 12582912);
  u16* qb  = (u16*)(ws + 16121856);
  u16* kb  = (u16*)(ws + 28704768);
  u16* vTb = (u16*)(ws + 41287680);

  hipLaunchKernelGGL(cvt_x_kernel, dim3(3072), dim3(256), 0, stream, x, xb);
  hipLaunchKernelGGL(cvt_wT_kernel, dim3(9, 192), dim3(256), 0, stream, W, WbT);
  hipLaunchKernelGGL(gemm_qkv_kernel, dim3(64, 18), dim3(256), 0, stream,
                     xb, WbT, bias, qb, kb, vTb);
  hipLaunchKernelGGL(attn_kernel, dim3(96, 8), dim3(256), 0, stream, qb, kb, vTb, out);
}